// Round 4
// baseline (701.696 us; speedup 1.0000x reference)
//
#include <hip/hip_runtime.h>
#include <math.h>

#define SIGMA_BOOST 2.0f
#define EPSILON 1e-6f

// ---------------------------------------------------------------------------
// Per-t parameters {mean_row, mean_col, sigma, pvalue}. Numerics FROZEN from
// the passing round-1 kernel (absmax 9.31 vs threshold 10.48 — index flips at
// round-half boundaries are the error source; do not perturb).
// ---------------------------------------------------------------------------
__device__ __forceinline__ float4 compute_param(const float2* __restrict__ pmeans,
                                                const float* __restrict__ psigmas,
                                                const float* __restrict__ pvalues,
                                                int t, int N) {
    float2 pm = pmeans[t];
    float scale = (float)(N - 1);
    float m0 = __fmul_rn(__fdiv_rn(1.0f, __fadd_rn(1.0f, expf(-pm.x))), scale);
    float m1 = __fmul_rn(__fdiv_rn(1.0f, __fadd_rn(1.0f, expf(-pm.y))), scale);
    float z  = __fadd_rn(psigmas[t], SIGMA_BOOST);
    float sp = __fadd_rn(fmaxf(z, 0.0f), log1pf(expf(-fabsf(z))));
    float sg = __fmul_rn(__fadd_rn(sp, EPSILON), (float)N);
    return make_float4(m0, m1, sg, pvalues[t]);
}

__global__ void params_kernel(const float2* __restrict__ pmeans,
                              const float* __restrict__ psigmas,
                              const float* __restrict__ pvalues,
                              float4* __restrict__ params, int N) {
    int t = blockIdx.x * blockDim.x + threadIdx.x;
    if (t < N) params[t] = compute_param(pmeans, psigmas, pvalues, t, N);
}

// ---------------------------------------------------------------------------
// Round 4: FLAT decomposition. The three per-row-mega-block variants (r1-r3)
// all landed 65-86us with every pipe idle -> the 1-2 block/CU barrier-phased
// structure is the wall. Here: 256-thread blocks, no LDS, no barriers,
// 8 items/thread, scatter via hardware global fp32 atomics (agent scope).
//   row   = blockIdx % B  -> with B%8==0 all chunks of a row map to the SAME
//                            XCD under round-robin dispatch (L2 locality for
//                            the x-row gathers and y-row atomics; perf only).
//   chunk = blockIdx / B  -> which 1024-float4 slice of the noise row.
// Each thread: U4 noise float4s (2 items each) + 2*U4 param float4s issued
// up front, then indices, then gathers (L1/L2-hot 64KB row), then atomics.
// y must be pre-zeroed (hipMemsetAsync in kernel_launch).
// ---------------------------------------------------------------------------
template <bool INLINE_PARAMS, int U4>
__launch_bounds__(256)
__global__ void contract_atomic(const float* __restrict__ x,
                                const float4* __restrict__ noise4,
                                const float4* __restrict__ params,
                                const float2* __restrict__ pmeans,
                                const float* __restrict__ psigmas,
                                const float* __restrict__ pvalues,
                                float* __restrict__ y, int N, int B) {
    const int nthr = 256;
    const int tid = threadIdx.x;
    const int row = (int)(blockIdx.x % (unsigned)B);
    const int chunk = (int)(blockIdx.x / (unsigned)B);
    const int half = N >> 1;                    // noise float4s per row (2 items each)
    const int jbase = chunk * (nthr * U4) + tid;

    const float4* nb4 = noise4 + (size_t)row * (size_t)half;
    const float*  xb  = x + (size_t)row * (size_t)N;
    float*        yb  = y + (size_t)row * (size_t)N;
    const float fN1 = (float)(N - 1);

    // --- issue all long-latency loads (3*U4 independent vmem ops) ---
    int j[U4];
    float4 nv[U4], pa[U4], pb[U4];
#pragma unroll
    for (int u = 0; u < U4; ++u) {
        j[u] = jbase + u * nthr;
        int jj = (j[u] < half) ? j[u] : (half - 1);   // clamped load, atomic guarded below
        nv[u] = nb4[jj];
        if (INLINE_PARAMS) {
            pa[u] = compute_param(pmeans, psigmas, pvalues, 2 * jj, N);
            pb[u] = compute_param(pmeans, psigmas, pvalues, 2 * jj + 1, N);
        } else {
            pa[u] = params[2 * jj];
            pb[u] = params[2 * jj + 1];
        }
    }

    // --- indices: sample = mean + sigma*noise, UNFUSED mul+add (frozen);
    //     rintf = half-to-even = np.round; clamp in float ---
    int r[2 * U4], c[2 * U4];
    float pv[2 * U4];
#pragma unroll
    for (int u = 0; u < U4; ++u) {
        float s0 = __fadd_rn(pa[u].x, __fmul_rn(pa[u].z, nv[u].x));
        float s1 = __fadd_rn(pa[u].y, __fmul_rn(pa[u].z, nv[u].y));
        r[2 * u] = (int)fminf(fmaxf(rintf(s0), 0.f), fN1);
        c[2 * u] = (int)fminf(fmaxf(rintf(s1), 0.f), fN1);
        pv[2 * u] = pa[u].w;
        float s2 = __fadd_rn(pb[u].x, __fmul_rn(pb[u].z, nv[u].z));
        float s3 = __fadd_rn(pb[u].y, __fmul_rn(pb[u].z, nv[u].w));
        r[2 * u + 1] = (int)fminf(fmaxf(rintf(s2), 0.f), fN1);
        c[2 * u + 1] = (int)fminf(fmaxf(rintf(s3), 0.f), fN1);
        pv[2 * u + 1] = pb[u].w;
    }

    // --- gathers: 2*U4 independent 4B loads in the L1/L2-hot 64KB row ---
    float xv[2 * U4];
#pragma unroll
    for (int k = 0; k < 2 * U4; ++k) xv[k] = xb[c[k]];

    // --- scatter: hardware global fp32 atomic add (agent scope) ---
#pragma unroll
    for (int k = 0; k < 2 * U4; ++k) {
        if (j[k >> 1] < half) {
            __hip_atomic_fetch_add(&yb[r[k]], __fmul_rn(pv[k], xv[k]),
                                   __ATOMIC_RELAXED, __HIP_MEMORY_SCOPE_AGENT);
        }
    }
}

extern "C" void kernel_launch(void* const* d_in, const int* in_sizes, int n_in,
                              void* d_out, int out_size, void* d_ws, size_t ws_size,
                              hipStream_t stream) {
    const float*  x       = (const float*)d_in[0];
    const float2* noise   = (const float2*)d_in[1];
    const float2* pmeans  = (const float2*)d_in[2];
    const float*  psigmas = (const float*)d_in[3];
    const float*  pvalues = (const float*)d_in[4];
    float* y = (float*)d_out;

    const int N = in_sizes[3];          // psigmas is (N,)
    const int B = in_sizes[0] / N;      // x is (B,N)

    const size_t params_bytes = (size_t)N * sizeof(float4);
    const bool use_ws = (ws_size >= params_bytes) && (d_ws != nullptr);

    // y is re-poisoned 0xAA before every timed launch -> zero it (capturable).
    (void)hipMemsetAsync(d_out, 0, (size_t)out_size * sizeof(float), stream);

    constexpr int U4 = 4;                        // 8 items/thread
    const int nthr = 256;
    const int items_per_block = 2 * nthr * U4;   // 2048
    const int chunks = (N + items_per_block - 1) / items_per_block;  // 8 at N=16384
    const int grid = B * chunks;                 // 4096

    float4* params = (float4*)d_ws;
    if (use_ws) {
        params_kernel<<<(N + 255) / 256, 256, 0, stream>>>(pmeans, psigmas, pvalues, params, N);
        contract_atomic<false, U4><<<grid, nthr, 0, stream>>>(
            x, (const float4*)noise, params, nullptr, nullptr, nullptr, y, N, B);
    } else {
        contract_atomic<true, U4><<<grid, nthr, 0, stream>>>(
            x, (const float4*)noise, nullptr, pmeans, psigmas, pvalues, y, N, B);
    }
}

// Round 6
// 179.947 us; speedup vs baseline: 3.8995x; 3.8995x over previous
//
#include <hip/hip_runtime.h>
#include <math.h>

#define SIGMA_BOOST 2.0f
#define EPSILON 1e-6f

// bf16 conversion via raw bit ops (ROCm's __hip_bfloat16 member layout varies
// across versions; this is version-proof and exactly RNE).
__device__ __forceinline__ unsigned short f32_to_bf16(float f) {
    unsigned u = __float_as_uint(f);
    unsigned rounding = 0x7FFFu + ((u >> 16) & 1u);   // round-to-nearest-even
    return (unsigned short)((u + rounding) >> 16);
}
__device__ __forceinline__ float bf16_to_f32(unsigned short h) {
    return __uint_as_float((unsigned)h << 16);
}

// ---------------------------------------------------------------------------
// Per-t parameters {mean_row, mean_col, sigma, pvalue}. Numerics FROZEN from
// the passing round-1 kernel (absmax 9.31 vs threshold 10.48 — index flips at
// round-half boundaries are the error source; do not perturb).
// ---------------------------------------------------------------------------
__device__ __forceinline__ float4 compute_param(const float2* __restrict__ pmeans,
                                                const float* __restrict__ psigmas,
                                                const float* __restrict__ pvalues,
                                                int t, int N) {
    float2 pm = pmeans[t];
    float scale = (float)(N - 1);
    float m0 = __fmul_rn(__fdiv_rn(1.0f, __fadd_rn(1.0f, expf(-pm.x))), scale);
    float m1 = __fmul_rn(__fdiv_rn(1.0f, __fadd_rn(1.0f, expf(-pm.y))), scale);
    float z  = __fadd_rn(psigmas[t], SIGMA_BOOST);
    float sp = __fadd_rn(fmaxf(z, 0.0f), log1pf(expf(-fabsf(z))));
    float sg = __fmul_rn(__fadd_rn(sp, EPSILON), (float)N);
    return make_float4(m0, m1, sg, pvalues[t]);
}

__global__ void params_kernel(const float2* __restrict__ pmeans,
                              const float* __restrict__ psigmas,
                              const float* __restrict__ pvalues,
                              float4* __restrict__ params, int N) {
    int t = blockIdx.x * blockDim.x + threadIdx.x;
    if (t < N) params[t] = compute_param(pmeans, psigmas, pvalues, t, N);
}

// ---------------------------------------------------------------------------
// Round 6 (= round-5 theory, build fixed): split-row blocks.
// Evidence: r1 (global divergent gathers, 2 blk/CU) = 65us, limited by
// L1-miss handling on scattered x gathers; r2 (LDS gathers, 1 blk/CU) = 68us
// with HALF the blocks -> LDS-gather structure ~2x better per block but
// 128KB LDS halved occupancy. r4: global atomics catastrophic (WRITE 262MB).
// Fix: 2 blocks per row. Each block:
//   LDS = [y-half acc: N/2 fp32 = 32KB][x row as bf16: N*2B = 32KB] = 64KB
//       -> 2 blocks/CU restored; gathers AND scatters stay in LDS.
//   Streams the FULL noise row; gather+atomic predicated on r in its half.
//   bf16 x-stage perturbs only VALUES (~0.4% rel), never indices.
// Pairing (row, row+B): B%8==0 -> same XCD -> 2nd read of noise/x hits L2/L3.
// __launch_bounds__(1024,8): cap 64 VGPR -> guarantee 8 waves/EU = 2 blk/CU.
// ---------------------------------------------------------------------------
template <bool INLINE_PARAMS>
__launch_bounds__(1024, 8)
__global__ void contract_split(const float* __restrict__ x,
                               const float4* __restrict__ noise4,
                               const float4* __restrict__ params,
                               const float2* __restrict__ pmeans,
                               const float* __restrict__ psigmas,
                               const float* __restrict__ pvalues,
                               float* __restrict__ y, int N, int B) {
    const int nthr  = 1024;
    const int tid   = threadIdx.x;
    const int row   = (int)(blockIdx.x % (unsigned)B);
    const int half  = (int)(blockIdx.x / (unsigned)B);
    const int halfN = N >> 1;
    const int rlo   = half * halfN;

    extern __shared__ char lds[];
    float* lacc = (float*)lds;                                 // halfN fp32
    unsigned short* lx = (unsigned short*)(lds + (size_t)halfN * 4); // N bf16

    // --- zero the half-row accumulator (float4-vectorized) ---
    float4* lacc4 = (float4*)lacc;
    const int h4 = halfN >> 2;
    for (int i = tid; i < h4; i += nthr) lacc4[i] = make_float4(0.f, 0.f, 0.f, 0.f);

    // --- stage full x row as bf16 (coalesced float4 in, 8B ds_write out) ---
    const float4* xb4 = (const float4*)(x + (size_t)row * N);
    ushort4* lx4 = (ushort4*)lx;
    const int n4 = N >> 2;
    for (int i = tid; i < n4; i += nthr) {
        float4 v = xb4[i];
        ushort4 o;
        o.x = f32_to_bf16(v.x);
        o.y = f32_to_bf16(v.y);
        o.z = f32_to_bf16(v.z);
        o.w = f32_to_bf16(v.w);
        lx4[i] = o;
    }
    __syncthreads();

    const float4* nb4 = noise4 + (size_t)row * (size_t)(N >> 1); // N/2 float4s
    const float fN1 = (float)(N - 1);
    const int nf4 = N >> 11;            // float4s per thread = (N/2)/1024

    // process 2 noise-float4s (4 items) per iteration for MLP
    for (int u = 0; u < nf4; u += 2) {
        const int j0 = tid + (u + 0) * nthr;
        const int j1 = tid + (u + 1) * nthr;
        // issue all 6 global loads up front
        float4 nv0 = nb4[j0];
        float4 nv1 = nb4[j1];
        float4 pa0, pb0, pa1, pb1;
        if (INLINE_PARAMS) {
            pa0 = compute_param(pmeans, psigmas, pvalues, 2 * j0,     N);
            pb0 = compute_param(pmeans, psigmas, pvalues, 2 * j0 + 1, N);
            pa1 = compute_param(pmeans, psigmas, pvalues, 2 * j1,     N);
            pb1 = compute_param(pmeans, psigmas, pvalues, 2 * j1 + 1, N);
        } else {
            pa0 = params[2 * j0];
            pb0 = params[2 * j0 + 1];
            pa1 = params[2 * j1];
            pb1 = params[2 * j1 + 1];
        }

        float sx[4], sy[4], pv[4];
        sx[0] = __fadd_rn(pa0.x, __fmul_rn(pa0.z, nv0.x));
        sy[0] = __fadd_rn(pa0.y, __fmul_rn(pa0.z, nv0.y));
        pv[0] = pa0.w;
        sx[1] = __fadd_rn(pb0.x, __fmul_rn(pb0.z, nv0.z));
        sy[1] = __fadd_rn(pb0.y, __fmul_rn(pb0.z, nv0.w));
        pv[1] = pb0.w;
        sx[2] = __fadd_rn(pa1.x, __fmul_rn(pa1.z, nv1.x));
        sy[2] = __fadd_rn(pa1.y, __fmul_rn(pa1.z, nv1.y));
        pv[2] = pa1.w;
        sx[3] = __fadd_rn(pb1.x, __fmul_rn(pb1.z, nv1.z));
        sy[3] = __fadd_rn(pb1.y, __fmul_rn(pb1.z, nv1.w));
        pv[3] = pb1.w;

#pragma unroll
        for (int k = 0; k < 4; ++k) {
            // rintf = half-to-even = np.round; UNFUSED mul+add above (frozen)
            int r = (int)fminf(fmaxf(rintf(sx[k]), 0.f), fN1);
            int c = (int)fminf(fmaxf(rintf(sy[k]), 0.f), fN1);
            unsigned rr = (unsigned)(r - rlo);
            if (rr < (unsigned)halfN) {
                float xv = bf16_to_f32(lx[c]);
                atomicAdd(&lacc[rr], __fmul_rn(pv[k], xv));
            }
        }
    }
    __syncthreads();

    // --- coalesced write-out of this block's half row ---
    float4* yb4 = (float4*)(y + (size_t)row * N + rlo);
    for (int i = tid; i < h4; i += nthr) yb4[i] = lacc4[i];
}

// ---------------------------------------------------------------------------
// Fallback (round-1 structure, known-good 65us): any N, LDS = full-row acc.
// ---------------------------------------------------------------------------
template <bool INLINE_PARAMS>
__launch_bounds__(1024, 1)
__global__ void contract_kernel(const float* __restrict__ x,
                                const float2* __restrict__ noise,
                                const float4* __restrict__ params,
                                const float2* __restrict__ pmeans,
                                const float* __restrict__ psigmas,
                                const float* __restrict__ pvalues,
                                float* __restrict__ y, int N) {
    extern __shared__ float ly[];
    const int b = blockIdx.x;
    const int tid = threadIdx.x;
    const int nthr = blockDim.x;

    float4* ly4 = (float4*)ly;
    const int n4 = N >> 2;
    for (int i = tid; i < n4; i += nthr) ly4[i] = make_float4(0.f, 0.f, 0.f, 0.f);
    __syncthreads();

    const float*  xb = x + (size_t)b * N;
    const float2* nb = noise + (size_t)b * N;
    const float fN1 = (float)(N - 1);

    for (int t = tid; t < N; t += nthr) {
        float4 p = INLINE_PARAMS ? compute_param(pmeans, psigmas, pvalues, t, N)
                                 : params[t];
        float2 nz = nb[t];
        float s0 = __fadd_rn(p.x, __fmul_rn(p.z, nz.x));
        float s1 = __fadd_rn(p.y, __fmul_rn(p.z, nz.y));
        int r = (int)fminf(fmaxf(rintf(s0), 0.0f), fN1);
        int c = (int)fminf(fmaxf(rintf(s1), 0.0f), fN1);
        atomicAdd(&ly[r], __fmul_rn(p.w, xb[c]));
    }
    __syncthreads();

    float4* yb4 = (float4*)(y + (size_t)b * N);
    for (int i = tid; i < n4; i += nthr) yb4[i] = ly4[i];
}

extern "C" void kernel_launch(void* const* d_in, const int* in_sizes, int n_in,
                              void* d_out, int out_size, void* d_ws, size_t ws_size,
                              hipStream_t stream) {
    const float*  x       = (const float*)d_in[0];
    const float2* noise   = (const float2*)d_in[1];
    const float2* pmeans  = (const float2*)d_in[2];
    const float*  psigmas = (const float*)d_in[3];
    const float*  pvalues = (const float*)d_in[4];
    float* y = (float*)d_out;

    const int N = in_sizes[3];          // psigmas is (N,)
    const int B = in_sizes[0] / N;      // x is (B,N)

    const size_t params_bytes = (size_t)N * sizeof(float4);
    const bool use_ws = (ws_size >= params_bytes) && (d_ws != nullptr);

    float4* params = (float4*)d_ws;
    if (use_ws)
        params_kernel<<<(N + 255) / 256, 256, 0, stream>>>(pmeans, psigmas, pvalues, params, N);

    // fast path: N multiple of 4096 (even float4s/thread) and 64KB LDS fits
    const size_t split_lds = 4 * (size_t)N;   // halfN*4 (acc) + N*2 (bf16 x)
    if ((N % 4096) == 0 && split_lds <= 65536) {
        if (use_ws) {
            contract_split<false><<<2 * B, 1024, split_lds, stream>>>(
                x, (const float4*)noise, params, nullptr, nullptr, nullptr, y, N, B);
        } else {
            contract_split<true><<<2 * B, 1024, split_lds, stream>>>(
                x, (const float4*)noise, nullptr, pmeans, psigmas, pvalues, y, N, B);
        }
    } else {
        const size_t acc_lds = (size_t)N * sizeof(float);
        if (use_ws) {
            contract_kernel<false><<<B, 1024, acc_lds, stream>>>(
                x, noise, params, nullptr, nullptr, nullptr, y, N);
        } else {
            contract_kernel<true><<<B, 1024, acc_lds, stream>>>(
                x, noise, nullptr, pmeans, psigmas, pvalues, y, N);
        }
    }
}